// Round 10
// baseline (274.929 us; speedup 1.0000x reference)
//
#include <hip/hip_runtime.h>
#include <hip/hip_bf16.h>

#define DD 6
#define FF 64
#define NS 30     // 2*D*RANK + D
#define TS16 32   // bf16 elements per table row (64 B)
#define UPB 32    // units per block in precompute

typedef float fx4 __attribute__((ext_vector_type(4)));

__device__ __forceinline__ float fast_sigmoid(float v) {
    return __builtin_amdgcn_rcpf(1.0f + __expf(-v));
}
__device__ __forceinline__ void nt_store4(float* p, float a, float b, float c, float d) {
    fx4 v = {a, b, c, d};
    __builtin_nontemporal_store(v, (fx4*)p);
}

// ---- precompute body (R5-proven) ----
__device__ __forceinline__ void precompute_body(
    const float* __restrict__ x, const float* __restrict__ e,
    const float* __restrict__ W, const float* __restrict__ bias,
    __hip_bfloat16* __restrict__ xW, __hip_bfloat16* __restrict__ eW,
    int N, int E, int nbN, int blk)
{
    __shared__ float means[UPB][68];
    bool isNode = blk < nbN;
    int ucount  = isNode ? N : E;
    int ubase   = (isNode ? blk : (blk - nbN)) * UPB;
    const float* src = isNode ? x : e;
    const float* Wp  = W + (isNode ? 0 : FF * NS);
    __hip_bfloat16* dst = isNode ? xW : eW;

    int tid = threadIdx.x, wid = tid >> 6, lane = tid & 63;

    #pragma unroll
    for (int i = 0; i < 8; ++i) {
        int s = wid * 8 + i;
        int u = ubase + s;
        float m = 0.f;
        if (u < ucount) {
            const float* p = src + (size_t)u * (DD * FF) + lane;
            #pragma unroll
            for (int d = 0; d < DD; ++d) m += p[d * FF];
        }
        means[s][lane] = m * (1.0f / 6.0f);
    }
    __syncthreads();

    int j30 = lane & 31;
    bool jval = j30 < NS;
    int j = jval ? j30 : 0;
    float wreg[FF];
    #pragma unroll
    for (int f = 0; f < FF; ++f) wreg[f] = Wp[f * NS + j];   // 15 KB, L1-resident
    float bj = isNode ? bias[j] : 0.f;

    #pragma unroll
    for (int t = 0; t < 4; ++t) {
        int sl = wid * 8 + 2 * t + (lane >> 5);
        int u  = ubase + sl;
        const fx4* mp4 = (const fx4*)(&means[sl][0]);
        float o = bj;
        #pragma unroll
        for (int q = 0; q < 16; ++q) {
            fx4 m4 = mp4[q];
            o = fmaf(m4.x, wreg[4 * q + 0], o);
            o = fmaf(m4.y, wreg[4 * q + 1], o);
            o = fmaf(m4.z, wreg[4 * q + 2], o);
            o = fmaf(m4.w, wreg[4 * q + 3], o);
        }
        if (jval && u < ucount)
            dst[(size_t)u * TS16 + j30] = __float2bfloat16(o);
    }
}

// ---- single-stream idx body: one output stream per block, 32 B per thread ----
__device__ __forceinline__ void idx_stream_body(
    const int* __restrict__ ind, float* __restrict__ outp,
    int tot, int ib, bool isDiv)
{
    int g = (ib * 256 + (int)threadIdx.x) * 8;
    if (g >= tot) return;
    #pragma unroll
    for (int h = 0; h < 2; ++h) {
        int gg = g + h * 4;
        if (gg < tot) {
            int l = gg / 36;
            int m = gg - l * 36;                 // 4-aligned, chunk stays in row l
            float base = (float)(6 * ind[l]);
            float v[4];
            #pragma unroll
            for (int i = 0; i < 4; ++i) {
                int mm = m + i;
                int q6 = mm / 6;
                v[i] = base + (float)(isDiv ? q6 : (mm - q6 * 6));
            }
            nt_store4(outp + gg, v[0], v[1], v[2], v[3]);
        }
    }
}

// ---- sheaf body (R9-proven wave-autonomous; dead rlds/clds removed) ----
__device__ __forceinline__ void sheaf_body(
    const int* __restrict__ rows, const int* __restrict__ cols,
    const __hip_bfloat16* __restrict__ xW, const __hip_bfloat16* __restrict__ eW,
    float* __restrict__ out_attr, int nnz, int blk)
{
    __shared__ float mlds[4][32 * 37];   // 18944 B -> 8 blocks/CU
    int tid = threadIdx.x, wid = tid >> 6, lane = tid & 63;
    int bb  = blk * 256;
    int k   = bb + tid;
    bool act = k < nnz;
    float mp[36];
    if (act) {
        int r = rows[k];
        int c = cols[k];
        const uint4* xp = (const uint4*)(xW + (size_t)r * TS16);
        const uint4* ep = (const uint4*)(eW + (size_t)c * TS16);
        uint4 xa0 = xp[0], xa1 = xp[1], xa2 = xp[2], xa3 = xp[3];
        uint4 ea0 = ep[0], ea1 = ep[1], ea2 = ep[2], ea3 = ep[3];
        uint wx[16] = {xa0.x, xa0.y, xa0.z, xa0.w, xa1.x, xa1.y, xa1.z, xa1.w,
                       xa2.x, xa2.y, xa2.z, xa2.w, xa3.x, xa3.y, xa3.z, xa3.w};
        uint we[16] = {ea0.x, ea0.y, ea0.z, ea0.w, ea1.x, ea1.y, ea1.z, ea1.w,
                       ea2.x, ea2.y, ea2.z, ea2.w, ea3.x, ea3.y, ea3.z, ea3.w};
        float s[NS];
        #pragma unroll
        for (int j2 = 0; j2 < NS; ++j2) {
            uint ux = (j2 & 1) ? (wx[j2 >> 1] & 0xffff0000u) : (wx[j2 >> 1] << 16);
            uint ue = (j2 & 1) ? (we[j2 >> 1] & 0xffff0000u) : (we[j2 >> 1] << 16);
            s[j2] = fast_sigmoid(__uint_as_float(ux) + __uint_as_float(ue));
        }
        #pragma unroll
        for (int i = 0; i < DD; ++i) {
            float a0 = s[i * 2], a1 = s[i * 2 + 1];
            #pragma unroll
            for (int jj = 0; jj < DD; ++jj) {
                float v = fmaf(a0, s[12 + jj * 2], a1 * s[13 + jj * 2]);
                if (i == jj) v += s[24 + i];
                mp[i * 6 + jj] = v;
            }
        }
    }
    float* wl = mlds[wid];
    int wbase = bb + wid * 64;
    #pragma unroll
    for (int h = 0; h < 2; ++h) {
        if (act && (lane >> 5) == h) {
            float* ml = wl + (lane & 31) * 37;   // lane*37%32: conflict-free
            #pragma unroll
            for (int m = 0; m < 36; ++m) ml[m] = mp[m];
        }
        asm volatile("" ::: "memory");           // staging before reads
        int b2  = wbase + h * 32;
        int cnt = nnz - b2; if (cnt > 32) cnt = 32;
        if (cnt > 0) {
            int tot = cnt * 36;
            float* gp = out_attr + (size_t)b2 * 36;
            for (int g = lane * 4; g < tot; g += 256) {
                int l = g / 36;
                int m = g - l * 36;
                const float* mlp = wl + l * 37 + m;
                nt_store4(gp + g, mlp[0], mlp[1], mlp[2], mlp[3]);
            }
        }
        asm volatile("" ::: "memory");           // reads before next half overwrites
    }
}

// ---- Kernel A: precompute only ----
__global__ __launch_bounds__(256) void precompute_kernel(
    const float* __restrict__ x, const float* __restrict__ e,
    const float* __restrict__ W, const float* __restrict__ bias,
    __hip_bfloat16* __restrict__ xW, __hip_bfloat16* __restrict__ eW,
    int N, int E, int nbN)
{
    precompute_body(x, e, W, bias, xW, eW, N, E, nbN, (int)blockIdx.x);
}

// ---- Kernel B: sheaf blocks interleaved 1-in-P among single-stream idx blocks.
// Gather-latency blocks are co-resident with write-stream filler at all times;
// each block writes exactly ONE contiguous output stream. ----
__global__ __launch_bounds__(256) void sheaf_idx_kernel(
    const int* __restrict__ rows, const int* __restrict__ cols,
    const __hip_bfloat16* __restrict__ xW, const __hip_bfloat16* __restrict__ eW,
    float* __restrict__ out_attr,
    float* __restrict__ out_idx0, float* __restrict__ out_idx1,
    int nnz, int nS, int P, int nI0)
{
    int i = (int)blockIdx.x;
    int q = i / P, rem = i - q * P;
    if (rem == 0 && q < nS) {
        sheaf_body(rows, cols, xW, eW, out_attr, nnz, q);
        return;
    }
    int nsee = q + (rem ? 1 : 0); if (nsee > nS) nsee = nS;
    int j = i - nsee;                       // bijective -> [0, 2*nI0)
    int tot = nnz * 36;
    if (j < nI0) idx_stream_body(rows, out_idx0, tot, j, true);
    else         idx_stream_body(cols, out_idx1, tot, j - nI0, false);
}

// ---- standalone idx kernels (fallback path only) ----
__global__ __launch_bounds__(256) void idx0_kernel(
    const int* __restrict__ rows, float* __restrict__ out_idx0, int tot)
{
    idx_stream_body(rows, out_idx0, tot, (int)blockIdx.x, true);
}
__global__ __launch_bounds__(256) void idx1_kernel(
    const int* __restrict__ cols, float* __restrict__ out_idx1, int tot)
{
    idx_stream_body(cols, out_idx1, tot, (int)blockIdx.x, false);
}

extern "C" void kernel_launch(void* const* d_in, const int* in_sizes, int n_in,
                              void* d_out, int out_size, void* d_ws, size_t ws_size,
                              hipStream_t stream)
{
    const float* x = (const float*)d_in[0];
    const float* e = (const float*)d_in[1];
    const float* W = (const float*)d_in[2];
    const float* b = (const float*)d_in[3];
    const int* hidx = (const int*)d_in[4];

    int N   = in_sizes[0] / (DD * FF);
    int E   = in_sizes[1] / (DD * FF);
    int nnz = in_sizes[4] / 2;
    const int* rows = hidx;
    const int* cols = hidx + nnz;

    float* out = (float*)d_out;
    size_t M = (size_t)nnz * 36;
    float* out_idx0 = out;
    float* out_idx1 = out + M;
    float* out_attr = out + 2 * M;

    size_t tableBytes = ((size_t)N + (size_t)E) * TS16 * sizeof(__hip_bfloat16);
    bool haveWs = (ws_size >= tableBytes);
    __hip_bfloat16* xW = haveWs ? (__hip_bfloat16*)d_ws
                                : (__hip_bfloat16*)out_idx0;   // fallback staging
    __hip_bfloat16* eW = xW + (size_t)N * TS16;

    int nbN = (N + UPB - 1) / UPB;
    int nbE = (E + UPB - 1) / UPB;
    int nbPre = nbN + nbE;
    int tot = nnz * 36;
    int nI0 = (tot + 2047) / 2048;          // blocks per idx stream (2048 floats each)
    int nS  = (nnz + 255) / 256;            // sheaf blocks

    precompute_kernel<<<nbPre, 256, 0, stream>>>(x, e, W, b, xW, eW, N, E, nbN);

    if (haveWs) {
        int grid = nS + 2 * nI0;
        int P = grid / nS; if (P < 1) P = 1;
        sheaf_idx_kernel<<<grid, 256, 0, stream>>>(
            rows, cols, xW, eW, out_attr, out_idx0, out_idx1, nnz, nS, P, nI0);
    } else {
        // Tables live in the idx0 output region: idx writes must come last.
        sheaf_idx_kernel<<<nS, 256, 0, stream>>>(
            rows, cols, xW, eW, out_attr, out_idx0, out_idx1, nnz, nS, 1, 0);
        idx0_kernel<<<nI0, 256, 0, stream>>>(rows, out_idx0, tot);
        idx1_kernel<<<nI0, 256, 0, stream>>>(cols, out_idx1, tot);
    }
}

// Round 11
// 123.404 us; speedup vs baseline: 2.2279x; 2.2279x over previous
//
#include <hip/hip_runtime.h>
#include <hip/hip_bf16.h>

#define DD 6
#define FF 64
#define NS 30     // 2*D*RANK + D
#define TS16 32   // bf16 elements per table row (64 B)
#define UPB 32    // units per block in precompute

typedef float fx4 __attribute__((ext_vector_type(4)));

__device__ __forceinline__ float fast_sigmoid(float v) {
    return __builtin_amdgcn_rcpf(1.0f + __expf(-v));
}
__device__ __forceinline__ void nt_store4(float* p, float a, float b, float c, float d) {
    fx4 v = {a, b, c, d};
    __builtin_nontemporal_store(v, (fx4*)p);
}

// ---- precompute body (R5-proven) ----
__device__ __forceinline__ void precompute_body(
    const float* __restrict__ x, const float* __restrict__ e,
    const float* __restrict__ W, const float* __restrict__ bias,
    __hip_bfloat16* __restrict__ xW, __hip_bfloat16* __restrict__ eW,
    int N, int E, int nbN, int blk)
{
    __shared__ float means[UPB][68];
    bool isNode = blk < nbN;
    int ucount  = isNode ? N : E;
    int ubase   = (isNode ? blk : (blk - nbN)) * UPB;
    const float* src = isNode ? x : e;
    const float* Wp  = W + (isNode ? 0 : FF * NS);
    __hip_bfloat16* dst = isNode ? xW : eW;

    int tid = threadIdx.x, wid = tid >> 6, lane = tid & 63;

    #pragma unroll
    for (int i = 0; i < 8; ++i) {
        int s = wid * 8 + i;
        int u = ubase + s;
        float m = 0.f;
        if (u < ucount) {
            const float* p = src + (size_t)u * (DD * FF) + lane;
            #pragma unroll
            for (int d = 0; d < DD; ++d) m += p[d * FF];
        }
        means[s][lane] = m * (1.0f / 6.0f);
    }
    __syncthreads();

    int j30 = lane & 31;
    bool jval = j30 < NS;
    int j = jval ? j30 : 0;
    float wreg[FF];
    #pragma unroll
    for (int f = 0; f < FF; ++f) wreg[f] = Wp[f * NS + j];   // 15 KB, L1-resident
    float bj = isNode ? bias[j] : 0.f;

    #pragma unroll
    for (int t = 0; t < 4; ++t) {
        int sl = wid * 8 + 2 * t + (lane >> 5);
        int u  = ubase + sl;
        const fx4* mp4 = (const fx4*)(&means[sl][0]);
        float o = bj;
        #pragma unroll
        for (int q = 0; q < 16; ++q) {
            fx4 m4 = mp4[q];
            o = fmaf(m4.x, wreg[4 * q + 0], o);
            o = fmaf(m4.y, wreg[4 * q + 1], o);
            o = fmaf(m4.z, wreg[4 * q + 2], o);
            o = fmaf(m4.w, wreg[4 * q + 3], o);
        }
        if (jval && u < ucount)
            dst[(size_t)u * TS16 + j30] = __float2bfloat16(o);
    }
}

// ---- single-stream idx body: ONE stream per block, 16 B/thread, each wave
// store instruction covers a fully-contiguous 1024 B span (NT-store invariant
// learned in R10: per-INSTRUCTION contiguity, not per-thread bytes) ----
__device__ __forceinline__ void idx_single_body(
    const int* __restrict__ ind, float* __restrict__ outp,
    int tot, int ib, bool isDiv)
{
    int g = (ib * 256 + (int)threadIdx.x) * 4;
    if (g >= tot) return;
    int l = g / 36;
    int m = g - l * 36;                      // 4-aligned; all 4 elems in row l
    float base = (float)(6 * ind[l]);
    float v[4];
    #pragma unroll
    for (int i = 0; i < 4; ++i) {
        int mm = m + i;
        int q6 = mm / 6;
        v[i] = base + (float)(isDiv ? q6 : (mm - q6 * 6));
    }
    nt_store4(outp + g, v[0], v[1], v[2], v[3]);
}

// ---- sheaf body (R9-proven wave-autonomous) ----
__device__ __forceinline__ void sheaf_body(
    const int* __restrict__ rows, const int* __restrict__ cols,
    const __hip_bfloat16* __restrict__ xW, const __hip_bfloat16* __restrict__ eW,
    float* __restrict__ out_attr, int nnz, int blk)
{
    __shared__ float mlds[4][32 * 37];
    int tid = threadIdx.x, wid = tid >> 6, lane = tid & 63;
    int bb  = blk * 256;
    int k   = bb + tid;
    bool act = k < nnz;
    float mp[36];
    if (act) {
        int r = rows[k];
        int c = cols[k];
        const uint4* xp = (const uint4*)(xW + (size_t)r * TS16);
        const uint4* ep = (const uint4*)(eW + (size_t)c * TS16);
        uint4 xa0 = xp[0], xa1 = xp[1], xa2 = xp[2], xa3 = xp[3];
        uint4 ea0 = ep[0], ea1 = ep[1], ea2 = ep[2], ea3 = ep[3];
        uint wx[16] = {xa0.x, xa0.y, xa0.z, xa0.w, xa1.x, xa1.y, xa1.z, xa1.w,
                       xa2.x, xa2.y, xa2.z, xa2.w, xa3.x, xa3.y, xa3.z, xa3.w};
        uint we[16] = {ea0.x, ea0.y, ea0.z, ea0.w, ea1.x, ea1.y, ea1.z, ea1.w,
                       ea2.x, ea2.y, ea2.z, ea2.w, ea3.x, ea3.y, ea3.z, ea3.w};
        float s[NS];
        #pragma unroll
        for (int j2 = 0; j2 < NS; ++j2) {
            uint ux = (j2 & 1) ? (wx[j2 >> 1] & 0xffff0000u) : (wx[j2 >> 1] << 16);
            uint ue = (j2 & 1) ? (we[j2 >> 1] & 0xffff0000u) : (we[j2 >> 1] << 16);
            s[j2] = fast_sigmoid(__uint_as_float(ux) + __uint_as_float(ue));
        }
        #pragma unroll
        for (int i = 0; i < DD; ++i) {
            float a0 = s[i * 2], a1 = s[i * 2 + 1];
            #pragma unroll
            for (int jj = 0; jj < DD; ++jj) {
                float v = fmaf(a0, s[12 + jj * 2], a1 * s[13 + jj * 2]);
                if (i == jj) v += s[24 + i];
                mp[i * 6 + jj] = v;
            }
        }
    }
    float* wl = mlds[wid];
    int wbase = bb + wid * 64;
    #pragma unroll
    for (int h = 0; h < 2; ++h) {
        if (act && (lane >> 5) == h) {
            float* ml = wl + (lane & 31) * 37;   // lane*37%32: conflict-free
            #pragma unroll
            for (int m = 0; m < 36; ++m) ml[m] = mp[m];
        }
        asm volatile("" ::: "memory");           // staging before reads
        int b2  = wbase + h * 32;
        int cnt = nnz - b2; if (cnt > 32) cnt = 32;
        if (cnt > 0) {
            int tot = cnt * 36;
            float* gp = out_attr + (size_t)b2 * 36;
            for (int g = lane * 4; g < tot; g += 256) {
                int l = g / 36;
                int m = g - l * 36;
                const float* mlp = wl + l * 37 + m;
                nt_store4(gp + g, mlp[0], mlp[1], mlp[2], mlp[3]);
            }
        }
        asm volatile("" ::: "memory");           // reads before next half overwrites
    }
}

// ---- Kernel A: precompute only ----
__global__ __launch_bounds__(256) void precompute_kernel(
    const float* __restrict__ x, const float* __restrict__ e,
    const float* __restrict__ W, const float* __restrict__ bias,
    __hip_bfloat16* __restrict__ xW, __hip_bfloat16* __restrict__ eW,
    int N, int E, int nbN)
{
    precompute_body(x, e, W, bias, xW, eW, N, E, nbN, (int)blockIdx.x);
}

// ---- Kernel B: sheaf blocks first (R9-proven order), then single-stream idx
// filler blocks: [nS, nS+nI) write idx0, [nS+nI, nS+2nI) write idx1 ----
__global__ __launch_bounds__(256) void sheaf_idx_kernel(
    const int* __restrict__ rows, const int* __restrict__ cols,
    const __hip_bfloat16* __restrict__ xW, const __hip_bfloat16* __restrict__ eW,
    float* __restrict__ out_attr,
    float* __restrict__ out_idx0, float* __restrict__ out_idx1,
    int nnz, int nS, int nI)
{
    int i = (int)blockIdx.x;
    int tot = nnz * 36;
    if (i < nS) {
        sheaf_body(rows, cols, xW, eW, out_attr, nnz, i);
    } else if (i < nS + nI) {
        idx_single_body(rows, out_idx0, tot, i - nS, true);
    } else {
        idx_single_body(cols, out_idx1, tot, i - nS - nI, false);
    }
}

// ---- standalone idx kernels (fallback path only) ----
__global__ __launch_bounds__(256) void idx0_kernel(
    const int* __restrict__ rows, float* __restrict__ out_idx0, int tot)
{
    idx_single_body(rows, out_idx0, tot, (int)blockIdx.x, true);
}
__global__ __launch_bounds__(256) void idx1_kernel(
    const int* __restrict__ cols, float* __restrict__ out_idx1, int tot)
{
    idx_single_body(cols, out_idx1, tot, (int)blockIdx.x, false);
}

extern "C" void kernel_launch(void* const* d_in, const int* in_sizes, int n_in,
                              void* d_out, int out_size, void* d_ws, size_t ws_size,
                              hipStream_t stream)
{
    const float* x = (const float*)d_in[0];
    const float* e = (const float*)d_in[1];
    const float* W = (const float*)d_in[2];
    const float* b = (const float*)d_in[3];
    const int* hidx = (const int*)d_in[4];

    int N   = in_sizes[0] / (DD * FF);
    int E   = in_sizes[1] / (DD * FF);
    int nnz = in_sizes[4] / 2;
    const int* rows = hidx;
    const int* cols = hidx + nnz;

    float* out = (float*)d_out;
    size_t M = (size_t)nnz * 36;
    float* out_idx0 = out;
    float* out_idx1 = out + M;
    float* out_attr = out + 2 * M;

    size_t tableBytes = ((size_t)N + (size_t)E) * TS16 * sizeof(__hip_bfloat16);
    bool haveWs = (ws_size >= tableBytes);
    __hip_bfloat16* xW = haveWs ? (__hip_bfloat16*)d_ws
                                : (__hip_bfloat16*)out_idx0;   // fallback staging
    __hip_bfloat16* eW = xW + (size_t)N * TS16;

    int nbN = (N + UPB - 1) / UPB;
    int nbE = (E + UPB - 1) / UPB;
    int nbPre = nbN + nbE;
    int tot = nnz * 36;
    int nI  = (tot + 1023) / 1024;          // single-stream idx blocks per stream
    int nS  = (nnz + 255) / 256;            // sheaf blocks

    precompute_kernel<<<nbPre, 256, 0, stream>>>(x, e, W, b, xW, eW, N, E, nbN);

    if (haveWs) {
        sheaf_idx_kernel<<<nS + 2 * nI, 256, 0, stream>>>(
            rows, cols, xW, eW, out_attr, out_idx0, out_idx1, nnz, nS, nI);
    } else {
        // Tables live in the idx0 output region: idx writes must come last.
        sheaf_idx_kernel<<<nS, 256, 0, stream>>>(
            rows, cols, xW, eW, out_attr, out_idx0, out_idx1, nnz, nS, 0);
        idx0_kernel<<<nI, 256, 0, stream>>>(rows, out_idx0, tot);
        idx1_kernel<<<nI, 256, 0, stream>>>(cols, out_idx1, tot);
    }
}